// Round 1
// 1205.307 us; speedup vs baseline: 1.1611x; 1.1611x over previous
//
#include <hip/hip_runtime.h>
#include <hip/hip_fp16.h>

#define BATCH   65536
#define NC      16
#define DDIM    64
#define GDIM    32
#define TILE    64

// One block = 16 waves = 16 concepts, one 64-batch tile, lane = batch.
// Phase 1: x tile staged in LDS as fp16 [b][j][d] in two j-halves (64 KB),
//          XOR-swizzled so batch-stride ds_read_b128 is conflict-light.
// Phase 2: FUSED mask+W1: h_pre is linear in m and m is linear over
//          j-halves, so accumulate hacc[32] directly from 8-wide d-octets
//          (mc[8]) — removes the m[64] array that was spilling to scratch
//          under the old 64-VGPR budget (WRITE_SIZE was 8.5x the output).
// Phase 3: ELU, then o = W2 @ h + b2 in registers (needs h[32]+o[64] live:
//          fits the 128-VGPR budget granted by __launch_bounds__(1024,4)
//          = 4 waves/EU = 1 block/CU).
// Phase 4: o[64] per lane -> LDS (fp32, 16-batch chunks, reusing the x
//          buffer) -> fully coalesced 1KB-per-wave-instruction stores.
extern "C" __global__ void __launch_bounds__(1024, 4)
causal_dag_kernel(const float* __restrict__ x, const float* __restrict__ A,
                  const float* __restrict__ W1, const float* __restrict__ b1,
                  const float* __restrict__ W2, const float* __restrict__ b2,
                  float* __restrict__ out)
{
    __shared__ __align__(16) unsigned char smem_raw[65536];
    __half* xs  = (__half*)smem_raw;      // phase 1-2: 64b x 8j x 64d fp16
    float*  osf = (float*)smem_raw;       // phase 4: 16b x 16c x 64d fp32

    const int t    = threadIdx.x;
    const int b0   = blockIdx.x * TILE;
    const int w    = __builtin_amdgcn_readfirstlane(t >> 6);  // concept, wave-uniform
    const int lane = t & 63;                                   // batch within tile
    const int sw   = lane & 7;

    const float* W1c = W1 + w * (GDIM * DDIM);
    const float* W2c = W2 + w * (DDIM * GDIM);
    const float* b1c = b1 + w * GDIM;
    const float* b2c = b2 + w * DDIM;

    // h_pre accumulator, folded across both j-halves and all d-octets
    float hacc[GDIM];
#pragma unroll
    for (int g = 0; g < GDIM; ++g) hacc[g] = b1c[g];

    for (int jh = 0; jh < 2; ++jh) {
        // ---- stage 8 concepts of x for the 64-batch tile, fp32->fp16 ----
#pragma unroll
        for (int p = 0; p < 8; ++p) {
            int f4 = p * 1024 + t;          // float4 index in 128 KB half-tile
            int bb = f4 >> 7;               // batch-local
            int r  = f4 & 127;
            int jp = r >> 4;                // j within half
            int d4 = r & 15;                // 4-float chunk of d
            const float4 v = *(const float4*)(
                x + ((size_t)(b0 + bb) * (NC * DDIM) + (jh * 8 + jp) * DDIM + d4 * 4));
            union { __half2 h2[2]; uint2 u; } pk;
            pk.h2[0] = __floats2half2_rn(v.x, v.y);
            pk.h2[1] = __floats2half2_rn(v.z, v.w);
            int dst = bb * 512 + jp * 64 + (((d4 >> 1) ^ (bb & 7)) << 3) + ((d4 & 1) << 2);
            *(uint2*)(xs + dst) = pk.u;
        }
        __syncthreads();

        // wave-uniform DAG column for this half (s_loads -> SGPRs)
        float a[8];
#pragma unroll
        for (int jp = 0; jp < 8; ++jp) a[jp] = A[(jh * 8 + jp) * NC + w];

        // ---- fused: mc[8] = sum_j a[j]*x[b,j,d-octet]; hacc += W1 . mc ----
        const __half* xb = xs + lane * 512;
#pragma unroll
        for (int dq = 0; dq < 8; ++dq) {
            float mc[8];
#pragma unroll
            for (int k = 0; k < 8; ++k) mc[k] = 0.f;
#pragma unroll
            for (int jp = 0; jp < 8; ++jp) {
                uint4 q = *(const uint4*)(xb + jp * 64 + ((dq ^ sw) << 3)); // ds_read_b128
                float2 f0 = __half22float2(*(__half2*)&q.x);
                float2 f1 = __half22float2(*(__half2*)&q.y);
                float2 f2 = __half22float2(*(__half2*)&q.z);
                float2 f3 = __half22float2(*(__half2*)&q.w);
                mc[0] = fmaf(a[jp], f0.x, mc[0]);
                mc[1] = fmaf(a[jp], f0.y, mc[1]);
                mc[2] = fmaf(a[jp], f1.x, mc[2]);
                mc[3] = fmaf(a[jp], f1.y, mc[3]);
                mc[4] = fmaf(a[jp], f2.x, mc[4]);
                mc[5] = fmaf(a[jp], f2.y, mc[5]);
                mc[6] = fmaf(a[jp], f3.x, mc[6]);
                mc[7] = fmaf(a[jp], f3.y, mc[7]);
            }
            const int d0 = dq * 8;
#pragma unroll
            for (int g = 0; g < GDIM; ++g) {
                float acc = hacc[g];
                acc = fmaf(W1c[g * DDIM + d0 + 0], mc[0], acc);
                acc = fmaf(W1c[g * DDIM + d0 + 1], mc[1], acc);
                acc = fmaf(W1c[g * DDIM + d0 + 2], mc[2], acc);
                acc = fmaf(W1c[g * DDIM + d0 + 3], mc[3], acc);
                acc = fmaf(W1c[g * DDIM + d0 + 4], mc[4], acc);
                acc = fmaf(W1c[g * DDIM + d0 + 5], mc[5], acc);
                acc = fmaf(W1c[g * DDIM + d0 + 6], mc[6], acc);
                acc = fmaf(W1c[g * DDIM + d0 + 7], mc[7], acc);
                hacc[g] = acc;
            }
        }
        if (jh == 0) __syncthreads();   // everyone done reading before restage
    }

    // ---- ELU in place ----
#pragma unroll
    for (int g = 0; g < GDIM; ++g)
        hacc[g] = hacc[g] > 0.f ? hacc[g] : (__expf(hacc[g]) - 1.f);

    // ---- o = W2c @ h + b2c, kept in registers ----
    __align__(16) float o[DDIM];
#pragma unroll
    for (int d = 0; d < DDIM; ++d) {
        float acc = b2c[d];
#pragma unroll
        for (int g = 0; g < GDIM; ++g) acc = fmaf(W2c[d * GDIM + g], hacc[g], acc);
        o[d] = acc;
    }

    // ---- epilogue: LDS transpose -> coalesced stores, 16 batches/chunk ----
    const int bl = lane & 15;     // batch-local within chunk
    const int lq = lane >> 4;     // which chunk this lane belongs to
    for (int q = 0; q < 4; ++q) {
        __syncthreads();          // xs dead (q=0) / previous chunk stored
        if (lq == q) {
#pragma unroll
            for (int d4 = 0; d4 < 16; ++d4) {
                // [bl][w][d] fp32, float4-chunk XOR-swizzled by bl
                int dst = bl * 1024 + w * 64 + ((d4 ^ bl) << 2);
                *(float4*)(osf + dst) = *(const float4*)(o + d4 * 4);
            }
        }
        __syncthreads();
        // 64 KB contiguous global region for these 16 batches
        float4* og = (float4*)(out + (size_t)(b0 + q * 16) * (NC * DDIM));
#pragma unroll
        for (int k = 0; k < 4; ++k) {
            int f  = k * 1024 + t;    // float4 idx in region; wave = 1 KB contiguous
            int bb = f >> 8;          // batch-local
            int r  = f & 255;
            int c  = r >> 4;
            int d4 = r & 15;
            og[f] = *(const float4*)(osf + bb * 1024 + c * 64 + ((d4 ^ bb) << 2));
        }
    }
}

extern "C" void kernel_launch(void* const* d_in, const int* in_sizes, int n_in,
                              void* d_out, int out_size, void* d_ws, size_t ws_size,
                              hipStream_t stream) {
    const float* x  = (const float*)d_in[0];
    const float* A  = (const float*)d_in[1];
    const float* W1 = (const float*)d_in[2];
    const float* b1 = (const float*)d_in[3];
    const float* W2 = (const float*)d_in[4];
    const float* b2 = (const float*)d_in[5];
    float* out = (float*)d_out;

    causal_dag_kernel<<<BATCH / TILE, 1024, 0, stream>>>(x, A, W1, b1, W2, b2, out);
}